// Round 3
// baseline (746.182 us; speedup 1.0000x reference)
//
#include <hip/hip_runtime.h>
#include <math.h>

typedef unsigned short ushortT;
typedef unsigned int uintT;
typedef __attribute__((ext_vector_type(8))) short short8;
typedef __attribute__((ext_vector_type(4))) float floatx4;

// Problem constants
#define DDIM 256
#define WWIN 64
#define BDIM 8
#define LDIM 8192
#define NWIN 128
#define CHUNK 8
#define NCHUNK 16
#define MAT ((size_t)DDIM * DDIM)

// 16B-slot XOR swizzle within a 128B LDS row (8 slots of 8 bf16 each).
#define SW8(row, slot) ((((slot) ^ ((row) & 7))) * 8)

__device__ __forceinline__ float dev_sigmoid(float x) {
    return 1.f / (1.f + expf(-x));
}

// f32 -> bf16 round-to-nearest-even
__device__ __forceinline__ ushortT f2b(float f) {
    uintT u = __float_as_uint(f);
    u += 0x7fff + ((u >> 16) & 1);
    return (ushortT)(u >> 16);
}

// ---------------------------------------------------------------------------
// hi/lo split helpers for ~f32-precision bf16 MFMA:
//   hi = truncate-to-bf16(x)  (exact: top 16 bits)
//   lo = RNE-bf16(x - hi)     (captures next ~9 bits; total rel err ~2^-17)
// Pair-packed little-endian: element k-even -> low 16 bits (matches MFMA
// K-pair packing used by sums_fused).
// ---------------------------------------------------------------------------
__device__ __forceinline__ void split2(float x0, float x1,
                                       uintT& hw, uintT& lw) {
    uintT u0 = __float_as_uint(x0), u1 = __float_as_uint(x1);
    uintT h0 = u0 & 0xffff0000u;
    uintT h1 = u1 & 0xffff0000u;
    hw = (h0 >> 16) | h1;
    float r0 = x0 - __uint_as_float(h0);
    float r1 = x1 - __uint_as_float(h1);
    lw = (uintT)f2b(r0) | ((uintT)f2b(r1) << 16);
}

// ---------------------------------------------------------------------------
// Split-bf16 MFMA scan matmul (replaces scalar-f32 mm_tile16):
//   Dst = scale*A + sgn*(A @ B) + (Add ? Add : 0)   (all 256x256 f32)
// Computed as Ah*Bh + Ah*Bl + Al*Bh (lo*lo dropped, ~2^-16 rel).
// Block = one 128x128 output tile (mq,nq), 4 waves of 64x64.
// ---------------------------------------------------------------------------
__device__ __forceinline__ void scan_mm(const float* __restrict__ A,
                                        const float* __restrict__ B,
                                        const float* __restrict__ Add,
                                        float* __restrict__ Dst,
                                        int mq, int nq,
                                        float scale, float sgn) {
    __shared__ __align__(16) ushortT Ah[128 * 64];
    __shared__ __align__(16) ushortT Al[128 * 64];
    __shared__ __align__(16) ushortT Bh[128 * 64];
    __shared__ __align__(16) ushortT Bl[128 * 64];

    int t = threadIdx.x;
    int lane = t & 63, wv = t >> 6;
    int wm = (wv & 1) * 64, wn = (wv >> 1) * 64;
    int m16 = lane & 15, g = lane >> 4;

    // A staging: 2 threads per row, 32 k each
    int ar = t >> 1;
    int akb = (t & 1) * 32;
    // B staging (transposed): 4 e-cols per thread, k-quads
    int be0 = (t >> 3) * 4;
    int bkq = t & 7;

    floatx4 acc[4][4];
#pragma unroll
    for (int i = 0; i < 4; i++)
#pragma unroll
        for (int j = 0; j < 4; j++) acc[i][j] = (floatx4)0.f;

    for (int c = 0; c < 4; c++) {
        int k0 = c * 64;
        __syncthreads();
        // ---- stage A [m][k] hi/lo (no transpose needed)
        {
            const float* Ap = A + (size_t)(mq * 128 + ar) * DDIM + k0 + akb;
#pragma unroll
            for (int s8 = 0; s8 < 4; s8++) {
                floatx4 v0 = *(const floatx4*)(Ap + s8 * 8);
                floatx4 v1 = *(const floatx4*)(Ap + s8 * 8 + 4);
                uint4 hw, lw;
                split2(v0[0], v0[1], hw.x, lw.x);
                split2(v0[2], v0[3], hw.y, lw.y);
                split2(v1[0], v1[1], hw.z, lw.z);
                split2(v1[2], v1[3], hw.w, lw.w);
                int slot = (akb >> 3) + s8;
                *(uint4*)&Ah[ar * 64 + SW8(ar, slot)] = hw;
                *(uint4*)&Al[ar * 64 + SW8(ar, slot)] = lw;
            }
        }
        // ---- stage B^T [e][k] hi/lo via 4k x 4e micro-tile transpose
#pragma unroll
        for (int p = 0; p < 2; p++) {
            int kq = bkq + 8 * p;
            int kk = k0 + kq * 4;
            const float* Bp = B + (size_t)kk * DDIM + nq * 128 + be0;
            floatx4 b0 = *(const floatx4*)Bp;
            floatx4 b1 = *(const floatx4*)(Bp + DDIM);
            floatx4 b2 = *(const floatx4*)(Bp + 2 * DDIM);
            floatx4 b3 = *(const floatx4*)(Bp + 3 * DDIM);
            int slot = kq >> 1;
            int half = (kq & 1) * 4;
#pragma unroll
            for (int j = 0; j < 4; j++) {
                uint2 hw, lw;
                split2(b0[j], b1[j], hw.x, lw.x);
                split2(b2[j], b3[j], hw.y, lw.y);
                int er = be0 + j;
                *(uint2*)&Bh[er * 64 + SW8(er, slot) + half] = hw;
                *(uint2*)&Bl[er * 64 + SW8(er, slot) + half] = lw;
            }
        }
        __syncthreads();
        // ---- MFMA: 3 products per fragment pair
#pragma unroll
        for (int ks = 0; ks < 2; ks++) {
            short8 afh[4], afl[4], bfh[4], bfl[4];
#pragma unroll
            for (int i = 0; i < 4; i++) {
                int row = wm + i * 16 + m16;
                afh[i] = *(const short8*)&Ah[row * 64 + SW8(row, 4 * ks + g)];
                afl[i] = *(const short8*)&Al[row * 64 + SW8(row, 4 * ks + g)];
            }
#pragma unroll
            for (int j = 0; j < 4; j++) {
                int row = wn + j * 16 + m16;
                bfh[j] = *(const short8*)&Bh[row * 64 + SW8(row, 4 * ks + g)];
                bfl[j] = *(const short8*)&Bl[row * 64 + SW8(row, 4 * ks + g)];
            }
#pragma unroll
            for (int i = 0; i < 4; i++)
#pragma unroll
                for (int j = 0; j < 4; j++) {
                    acc[i][j] = __builtin_amdgcn_mfma_f32_16x16x32_bf16(
                        afh[i], bfh[j], acc[i][j], 0, 0, 0);
                    acc[i][j] = __builtin_amdgcn_mfma_f32_16x16x32_bf16(
                        afh[i], bfl[j], acc[i][j], 0, 0, 0);
                    acc[i][j] = __builtin_amdgcn_mfma_f32_16x16x32_bf16(
                        afl[i], bfh[j], acc[i][j], 0, 0, 0);
                }
        }
    }

    bool hasScale = (scale != 0.f);
#pragma unroll
    for (int i = 0; i < 4; i++)
#pragma unroll
        for (int j = 0; j < 4; j++) {
            int row = mq * 128 + wm + i * 16 + g * 4;
            int col = nq * 128 + wn + j * 16 + m16;
#pragma unroll
            for (int r = 0; r < 4; r++) {
                size_t off = (size_t)(row + r) * DDIM + col;
                float v = sgn * acc[i][j][r];
                if (hasScale) v += scale * A[off];
                if (Add) v += Add[off];
                Dst[off] = v;
            }
        }
}

// copy one 128x128 tile of a 256x256 matrix
__device__ __forceinline__ void copy_tile128(const float* __restrict__ src,
                                             float* __restrict__ dst,
                                             int mq, int nq) {
    int t = threadIdx.x;
    int r = mq * 128 + (t >> 1);
    int c0 = nq * 128 + (t & 1) * 64;
    const float* s = src + (size_t)r * DDIM + c0;
    float* d = dst + (size_t)r * DDIM + c0;
#pragma unroll
    for (int j = 0; j < 16; j++)
        *(float4*)(d + j * 4) = *(const float4*)(s + j * 4);
}

// ---------------------------------------------------------------------------
// Fused sums GEMM:
//   Out[n][m][e] = sum_{r} Asrc[l(r)][m] * (gamma[l(r)] * Bsrc[l(r)][e])
// A-side + gammas register-prefetched across the K-chunk loop (T14); B inline.
// When Pinit != nullptr, chunk-start windows also emit P = a*I - Out.
// ---------------------------------------------------------------------------
__global__ __launch_bounds__(256, 2) void sums_fused(
    const float* __restrict__ Asrc,
    const float* __restrict__ Bsrc,
    const float* __restrict__ gammas,
    float* __restrict__ Out,
    float* __restrict__ Pinit,
    const float* __restrict__ alpha_raw) {
    int nq = blockIdx.x & 1;
    int mq = (blockIdx.x >> 1) & 1;
    int n = blockIdx.x >> 2;

    __shared__ __align__(16) ushortT Asm[128 * 64];
    __shared__ __align__(16) ushortT Bsm[128 * 64];

    int t = threadIdx.x;
    int lane = t & 63, wv = t >> 6;
    int wm = (wv & 1) * 64, wn = (wv >> 1) * 64;
    int m16 = lane & 15, g = lane >> 4;

    int d0 = (t >> 3) * 4;
    int rqb = t & 7;

    floatx4 acc[4][4];
#pragma unroll
    for (int i = 0; i < 4; i++)
#pragma unroll
        for (int j = 0; j < 4; j++) acc[i][j] = (floatx4)0.f;

    floatx4 pa[2][4], pgv[2];
    {
        size_t lbase = (size_t)n * WWIN;
#pragma unroll
        for (int p = 0; p < 2; p++) {
            int r0 = (rqb + 8 * p) * 4;
            const float* Ar = Asrc + (lbase + r0) * DDIM + mq * 128 + d0;
            pa[p][0] = *(const floatx4*)Ar;
            pa[p][1] = *(const floatx4*)(Ar + DDIM);
            pa[p][2] = *(const floatx4*)(Ar + 2 * DDIM);
            pa[p][3] = *(const floatx4*)(Ar + 3 * DDIM);
            pgv[p] = *(const floatx4*)(gammas + lbase + r0);
        }
    }

    for (int c = 0; c < 8; c++) {
        size_t lbase = (size_t)c * LDIM + n * WWIN;
        __syncthreads();
#pragma unroll
        for (int p = 0; p < 2; p++) {
            int rq = rqb + 8 * p;
            int r0 = rq * 4;
            const float* Br = Bsrc + (lbase + r0) * DDIM + nq * 128 + d0;
            floatx4 b0 = *(const floatx4*)Br;
            floatx4 b1 = *(const floatx4*)(Br + DDIM);
            floatx4 b2 = *(const floatx4*)(Br + 2 * DDIM);
            floatx4 b3 = *(const floatx4*)(Br + 3 * DDIM);
            floatx4 gv = pgv[p];
            b0 *= gv[0]; b1 *= gv[1]; b2 *= gv[2]; b3 *= gv[3];
            int slot = rq >> 1;
            int half = (rq & 1) * 4;
#pragma unroll
            for (int j = 0; j < 4; j++) {
                int dr = d0 + j;
                uint2 wa, wb;
                wa.x = (uintT)f2b(pa[p][0][j]) | ((uintT)f2b(pa[p][1][j]) << 16);
                wa.y = (uintT)f2b(pa[p][2][j]) | ((uintT)f2b(pa[p][3][j]) << 16);
                wb.x = (uintT)f2b(b0[j]) | ((uintT)f2b(b1[j]) << 16);
                wb.y = (uintT)f2b(b2[j]) | ((uintT)f2b(b3[j]) << 16);
                *(uint2*)&Asm[dr * 64 + SW8(dr, slot) + half] = wa;
                *(uint2*)&Bsm[dr * 64 + SW8(dr, slot) + half] = wb;
            }
        }
        if (c < 7) {
            size_t lb2 = lbase + LDIM;
#pragma unroll
            for (int p = 0; p < 2; p++) {
                int r0 = (rqb + 8 * p) * 4;
                const float* Ar = Asrc + (lb2 + r0) * DDIM + mq * 128 + d0;
                pa[p][0] = *(const floatx4*)Ar;
                pa[p][1] = *(const floatx4*)(Ar + DDIM);
                pa[p][2] = *(const floatx4*)(Ar + 2 * DDIM);
                pa[p][3] = *(const floatx4*)(Ar + 3 * DDIM);
                pgv[p] = *(const floatx4*)(gammas + lb2 + r0);
            }
        }
        __syncthreads();
#pragma unroll
        for (int ks = 0; ks < 2; ks++) {
            short8 af[4], bq[4];
#pragma unroll
            for (int i = 0; i < 4; i++) {
                int row = wm + i * 16 + m16;
                af[i] = *(const short8*)&Asm[row * 64 + SW8(row, 4 * ks + g)];
            }
#pragma unroll
            for (int j = 0; j < 4; j++) {
                int row = wn + j * 16 + m16;
                bq[j] = *(const short8*)&Bsm[row * 64 + SW8(row, 4 * ks + g)];
            }
#pragma unroll
            for (int i = 0; i < 4; i++)
#pragma unroll
                for (int j = 0; j < 4; j++)
                    acc[i][j] = __builtin_amdgcn_mfma_f32_16x16x32_bf16(
                        af[i], bq[j], acc[i][j], 0, 0, 0);
        }
    }

    float* Ob = Out + (size_t)n * MAT;
    bool doP = (Pinit != nullptr) && ((n & (CHUNK - 1)) == 0);
    float aSig = doP ? dev_sigmoid(alpha_raw[0]) : 0.f;
#pragma unroll
    for (int i = 0; i < 4; i++)
#pragma unroll
        for (int j = 0; j < 4; j++)
#pragma unroll
            for (int r = 0; r < 4; r++) {
                int row = mq * 128 + wm + i * 16 + g * 4 + r;
                int col = nq * 128 + wn + j * 16 + m16;
                float v = acc[i][j][r];
                Ob[(size_t)row * DDIM + col] = v;
                if (doP) {
                    float* Pb = Pinit + (size_t)n * MAT;
                    Pb[(size_t)row * DDIM + col] =
                        ((row == col) ? aSig : 0.f) - v;
                }
            }
}

// ---------------------------------------------------------------------------
// MFMA retrieval: out[l][o] = sum_d q[l][d] * M[n(l)][o][d]
// q tile register-prefetched across the d-chunk loop (T14); M inline.
// ---------------------------------------------------------------------------
__global__ __launch_bounds__(256, 2) void out_mfma(
    const float* __restrict__ q,
    const float* __restrict__ Ms,
    float* __restrict__ out) {
    int op = blockIdx.x & 1;
    int rp = (blockIdx.x >> 1) & 3;
    int n = blockIdx.x >> 3;

    __shared__ __align__(16) ushortT Qsm[128 * 64];
    __shared__ __align__(16) ushortT Msm[128 * 64];

    int t = threadIdx.x;
    int lane = t & 63, wv = t >> 6;
    int wm = (wv & 1) * 64, wn = (wv >> 1) * 64;
    int m16 = lane & 15, g = lane >> 4;
    int f4 = t & 15;

    const float* Mbase = Ms + (size_t)n * MAT + (size_t)(op * 128) * DDIM;

    floatx4 acc[4][4];
#pragma unroll
    for (int i = 0; i < 4; i++)
#pragma unroll
        for (int j = 0; j < 4; j++) acc[i][j] = (floatx4)0.f;

    floatx4 qv[8];
    {
#pragma unroll
        for (int p = 0; p < 8; p++) {
            int row = (t >> 4) + p * 16;
            int b = rp * 2 + (row >> 6);
            int l = b * LDIM + n * WWIN + (row & 63);
            qv[p] = *(const floatx4*)&q[(size_t)l * DDIM + f4 * 4];
        }
    }

    for (int c = 0; c < 4; c++) {
        int d0 = c * 64;
        __syncthreads();
#pragma unroll
        for (int p = 0; p < 8; p++) {
            int row = (t >> 4) + p * 16;
            uint2 o2;
            o2.x = (uintT)f2b(qv[p][0]) | ((uintT)f2b(qv[p][1]) << 16);
            o2.y = (uintT)f2b(qv[p][2]) | ((uintT)f2b(qv[p][3]) << 16);
            *(uint2*)&Qsm[row * 64 + SW8(row, f4 >> 1) + (f4 & 1) * 4] = o2;
        }
#pragma unroll
        for (int p = 0; p < 4; p++) {
            int o = (t >> 3) + p * 32;
            int dg = t & 7;
            const floatx4* src =
                (const floatx4*)&Mbase[(size_t)o * DDIM + d0 + dg * 8];
            floatx4 m0 = src[0];
            floatx4 m1 = src[1];
            uint4 w;
            w.x = (uintT)f2b(m0[0]) | ((uintT)f2b(m0[1]) << 16);
            w.y = (uintT)f2b(m0[2]) | ((uintT)f2b(m0[3]) << 16);
            w.z = (uintT)f2b(m1[0]) | ((uintT)f2b(m1[1]) << 16);
            w.w = (uintT)f2b(m1[2]) | ((uintT)f2b(m1[3]) << 16);
            *(uint4*)&Msm[o * 64 + SW8(o, dg)] = w;
        }
        if (c < 3) {
            int d1 = d0 + 64;
#pragma unroll
            for (int p = 0; p < 8; p++) {
                int row = (t >> 4) + p * 16;
                int b = rp * 2 + (row >> 6);
                int l = b * LDIM + n * WWIN + (row & 63);
                qv[p] = *(const floatx4*)&q[(size_t)l * DDIM + d1 + f4 * 4];
            }
        }
        __syncthreads();
#pragma unroll
        for (int ks = 0; ks < 2; ks++) {
            short8 af[4], bq[4];
#pragma unroll
            for (int i = 0; i < 4; i++) {
                int row = wm + i * 16 + m16;
                af[i] = *(const short8*)&Qsm[row * 64 + SW8(row, 4 * ks + g)];
            }
#pragma unroll
            for (int j = 0; j < 4; j++) {
                int row = wn + j * 16 + m16;
                bq[j] = *(const short8*)&Msm[row * 64 + SW8(row, 4 * ks + g)];
            }
#pragma unroll
            for (int i = 0; i < 4; i++)
#pragma unroll
                for (int j = 0; j < 4; j++)
                    acc[i][j] = __builtin_amdgcn_mfma_f32_16x16x32_bf16(
                        af[i], bq[j], acc[i][j], 0, 0, 0);
        }
    }

#pragma unroll
    for (int i = 0; i < 4; i++)
#pragma unroll
        for (int r = 0; r < 4; r++) {
            int row = wm + i * 16 + g * 4 + r;
            int b = rp * 2 + (row >> 6);
            size_t l = (size_t)b * LDIM + n * WWIN + (row & 63);
#pragma unroll
            for (int j = 0; j < 4; j++) {
                int col = op * 128 + wn + j * 16 + m16;
                out[l * DDIM + col] = acc[i][j][r];
            }
        }
}

// ---------------------------------------------------------------------------
// Scan kernels (now split-bf16 MFMA; 4 blocks of 128x128 per matmul target)
// ---------------------------------------------------------------------------
__global__ __launch_bounds__(256, 2) void phase1_kernel(
    const float* __restrict__ Skk,
    float* __restrict__ Q,
    float* __restrict__ P,
    const float* __restrict__ alpha_raw,
    int j) {
    float a = dev_sigmoid(alpha_raw[0]);
    int nq = blockIdx.x & 1;
    int mq = (blockIdx.x >> 1) & 1;
    int idx = blockIdx.x >> 2;
    int chunk = idx >> 1;
    int target = idx & 1;
    int n = chunk * CHUNK + j;
    const float* Bm = Skk + (size_t)n * MAT;
    const float* Ab;
    const float* Addp;
    float* Dp;
    if (target == 0) {
        Ab = P + (size_t)(n - 1) * MAT;
        Addp = nullptr;
        Dp = P + (size_t)n * MAT;
    } else {
        Ab = Q + (size_t)(n - 1) * MAT;
        Dp = Q + (size_t)n * MAT;
        Addp = Dp;
    }
    scan_mm(Ab, Bm, Addp, Dp, mq, nq, a, -1.f);
}

// Kogge-Stone tree over the 16 chunk carries. Operator:
//   Q'_c = Q_{c-s} * P_c + Q_c ;  P'_c = P_{c-s} * P_c   (c >= s; copy else)
__global__ __launch_bounds__(256, 2) void ks_kernel(
    const float* __restrict__ srcQ,
    const float* __restrict__ srcP,
    float* __restrict__ dstQ,
    float* __restrict__ dstP,
    size_t sQs, size_t sPs, size_t dQs, size_t dPs,
    int s, int qonly) {
    int nq = blockIdx.x & 1;
    int mq = (blockIdx.x >> 1) & 1;
    int idx = blockIdx.x >> 2;
    int kind = qonly ? 0 : (idx & 1);
    int c = qonly ? idx : (idx >> 1);
    const float* Ab;
    const float* Bm;
    const float* Addp;
    float* D;
    if (kind == 0) {
        D = dstQ + (size_t)c * dQs;
        if (c < s) {
            copy_tile128(srcQ + (size_t)c * sQs, D, mq, nq);
            return;
        }
        Ab = srcQ + (size_t)(c - s) * sQs;
        Bm = srcP + (size_t)c * sPs;
        Addp = srcQ + (size_t)c * sQs;
    } else {
        D = dstP + (size_t)c * dPs;
        if (c < s) {
            copy_tile128(srcP + (size_t)c * sPs, D, mq, nq);
            return;
        }
        Ab = srcP + (size_t)(c - s) * sPs;
        Bm = srcP + (size_t)c * sPs;
        Addp = nullptr;
    }
    scan_mm(Ab, Bm, Addp, D, mq, nq, 0.f, 1.f);
}

__global__ __launch_bounds__(256, 2) void phase3_kernel(
    float* __restrict__ Q,
    const float* __restrict__ P) {
    int nq = blockIdx.x & 1;
    int mq = (blockIdx.x >> 1) & 1;
    int w = blockIdx.x >> 2;
    int c = 1 + w / (CHUNK - 1);
    int j = w - (c - 1) * (CHUNK - 1);
    int n = c * CHUNK + j;
    int s = c * CHUNK - 1;
    float* d = Q + (size_t)n * MAT;
    scan_mm(Q + (size_t)s * MAT, P + (size_t)n * MAT, d, d, mq, nq, 0.f, 1.f);
}

// ---------------------------------------------------------------------------
extern "C" void kernel_launch(void* const* d_in, const int* in_sizes, int n_in,
                              void* d_out, int out_size, void* d_ws, size_t ws_size,
                              hipStream_t stream) {
    const float* keys    = (const float*)d_in[0];
    const float* values  = (const float*)d_in[1];
    const float* queries = (const float*)d_in[2];
    const float* gammas  = (const float*)d_in[3];
    const float* alpha   = (const float*)d_in[4];
    float* outp = (float*)d_out;

    // Workspace layout (112 MB peak):
    //  A [0,32M):   Skk f32
    //  B [32,64M):  Q f32 (Svk -> prefix -> final Ms)
    //  C [64,96M):  P f32
    //  D [96,112M): KS ping-pong tail buffers (T1Q,T1P,T2Q,T2P, 4MB each)
    char* ws = (char*)d_ws;
    float* Skk = (float*)ws;
    float* Q   = (float*)(ws + (size_t)32 * 1024 * 1024);
    float* P   = (float*)(ws + (size_t)64 * 1024 * 1024);
    char*  rD  = ws + (size_t)96 * 1024 * 1024;
    float* T1Q = (float*)rD;
    float* T1P = (float*)(rD + (size_t)4 * 1024 * 1024);
    float* T2Q = (float*)(rD + (size_t)8 * 1024 * 1024);
    float* T2P = (float*)(rD + (size_t)12 * 1024 * 1024);

    // 1) Skk = sum gamma k k^T ; chunk-start blocks also emit P = aI - Skk
    sums_fused<<<NWIN * 4, 256, 0, stream>>>(keys, keys, gammas, Skk, P, alpha);
    // 2) Svk = sum gamma v k^T -> Q
    sums_fused<<<NWIN * 4, 256, 0, stream>>>(values, keys, gammas, Q, nullptr,
                                             alpha);

    // 3) scan: chunk-local pass (split-bf16 MFMA)
    for (int j = 1; j < CHUNK; j++)
        phase1_kernel<<<NCHUNK * 2 * 4, 256, 0, stream>>>(Skk, Q, P, alpha, j);

    // 4) cross-chunk Kogge-Stone on the 16 tails (e_c = 8c+7)
    ks_kernel<<<32 * 4, 256, 0, stream>>>(Q + 7 * MAT, P + 7 * MAT, T1Q, T1P,
                                          8 * MAT, 8 * MAT, MAT, MAT, 1, 0);
    ks_kernel<<<32 * 4, 256, 0, stream>>>(T1Q, T1P, T2Q, T2P,
                                          MAT, MAT, MAT, MAT, 2, 0);
    ks_kernel<<<32 * 4, 256, 0, stream>>>(T2Q, T2P, T1Q, T1P,
                                          MAT, MAT, MAT, MAT, 4, 0);
    ks_kernel<<<16 * 4, 256, 0, stream>>>(T1Q, T1P, Q + 7 * MAT, nullptr,
                                          MAT, MAT, 8 * MAT, 0, 8, 1);

    // 5) broadcast tails into non-tail windows (split-bf16 MFMA)
    phase3_kernel<<<(NCHUNK - 1) * (CHUNK - 1) * 4, 256, 0, stream>>>(Q, P);

    // 6) retrieval (M converted f32->bf16 in-flight)
    out_mfma<<<NWIN * 8, 256, 0, stream>>>(queries, Q, outp);
}

// Round 5
// 488.716 us; speedup vs baseline: 1.5268x; 1.5268x over previous
//
#include <hip/hip_runtime.h>
#include <math.h>

typedef unsigned short ushortT;
typedef unsigned int uintT;
typedef __attribute__((ext_vector_type(8))) short short8;
typedef __attribute__((ext_vector_type(4))) float floatx4;

// Problem constants
#define DDIM 256
#define WWIN 64
#define BDIM 8
#define LDIM 8192
#define NWIN 128
#define CHUNK 4
#define NCHUNK 32
#define MAT ((size_t)DDIM * DDIM)

// 16B-slot XOR swizzle within a 128B LDS row (8 slots of 8 bf16 each).
#define SW8(row, slot) ((((slot) ^ ((row) & 7))) * 8)

__device__ __forceinline__ float dev_sigmoid(float x) {
    return 1.f / (1.f + expf(-x));
}

// f32 -> bf16 round-to-nearest-even
__device__ __forceinline__ ushortT f2b(float f) {
    uintT u = __float_as_uint(f);
    u += 0x7fff + ((u >> 16) & 1);
    return (ushortT)(u >> 16);
}

// hi/lo split: hi = truncate-to-bf16 (exact top 16 bits), lo = RNE-bf16 of
// the residual. Pair-packed little-endian (k-even in low 16 bits).
__device__ __forceinline__ void split2(float x0, float x1,
                                       uintT& hw, uintT& lw) {
    uintT u0 = __float_as_uint(x0), u1 = __float_as_uint(x1);
    uintT h0 = u0 & 0xffff0000u;
    uintT h1 = u1 & 0xffff0000u;
    hw = (h0 >> 16) | h1;
    float r0 = x0 - __uint_as_float(h0);
    float r1 = x1 - __uint_as_float(h1);
    lw = (uintT)f2b(r0) | ((uintT)f2b(r1) << 16);
}

// ---------------------------------------------------------------------------
// Split-bf16 MFMA scan matmul, 64x64 output tile (mt,nt) of a 256x256 target:
//   Dst = scale*A + sgn*(A @ B) + (Add ? Add : 0)
// Computed as Ah*Bh + Ah*Bl + Al*Bh (lo*lo dropped, ~2^-16 rel).
// Block = 256 threads, 4 waves of 32x32 (2x2 16x16 frags). LDS 32 KB.
// ---------------------------------------------------------------------------
__device__ __forceinline__ void scan64(ushortT* __restrict__ sm,
                                       const float* __restrict__ A,
                                       const float* __restrict__ B,
                                       const float* __restrict__ Add,
                                       float* __restrict__ Dst,
                                       int mt, int nt,
                                       float scale, float sgn) {
    ushortT* Ah = sm;
    ushortT* Al = sm + 4096;
    ushortT* Bh = sm + 8192;
    ushortT* Bl = sm + 12288;

    int t = threadIdx.x;
    int lane = t & 63, wv = t >> 6;
    int wm = (wv & 1) * 32, wn = (wv >> 1) * 32;
    int m16 = lane & 15, g = lane >> 4;

    // A staging: 4 threads per row, 16 k each
    int ar = t >> 2, akb = (t & 3) * 16;
    // B staging (transpose): 4 e-cols per thread, one k-quad
    int be0 = (t >> 4) * 4, bkq = t & 15;

    floatx4 acc[2][2];
#pragma unroll
    for (int i = 0; i < 2; i++)
#pragma unroll
        for (int j = 0; j < 2; j++) acc[i][j] = (floatx4)0.f;

    for (int c = 0; c < 4; c++) {
        int k0 = c * 64;
        __syncthreads();
        // ---- stage A [m][k] hi/lo
        {
            const float* Ap = A + (size_t)(mt * 64 + ar) * DDIM + k0 + akb;
#pragma unroll
            for (int h = 0; h < 2; h++) {
                floatx4 v0 = *(const floatx4*)(Ap + h * 8);
                floatx4 v1 = *(const floatx4*)(Ap + h * 8 + 4);
                uint4 hw, lw;
                split2(v0[0], v0[1], hw.x, lw.x);
                split2(v0[2], v0[3], hw.y, lw.y);
                split2(v1[0], v1[1], hw.z, lw.z);
                split2(v1[2], v1[3], hw.w, lw.w);
                int slot = (akb >> 3) + h;
                *(uint4*)&Ah[ar * 64 + SW8(ar, slot)] = hw;
                *(uint4*)&Al[ar * 64 + SW8(ar, slot)] = lw;
            }
        }
        // ---- stage B^T [e][k] hi/lo via 4k x 4e micro-tile transpose
        {
            int kk = k0 + bkq * 4;
            const float* Bp = B + (size_t)kk * DDIM + nt * 64 + be0;
            floatx4 b0 = *(const floatx4*)Bp;
            floatx4 b1 = *(const floatx4*)(Bp + DDIM);
            floatx4 b2 = *(const floatx4*)(Bp + 2 * DDIM);
            floatx4 b3 = *(const floatx4*)(Bp + 3 * DDIM);
            int slot = bkq >> 1, half = (bkq & 1) * 4;
#pragma unroll
            for (int j = 0; j < 4; j++) {
                uint2 hw, lw;
                split2(b0[j], b1[j], hw.x, lw.x);
                split2(b2[j], b3[j], hw.y, lw.y);
                int er = be0 + j;
                *(uint2*)&Bh[er * 64 + SW8(er, slot) + half] = hw;
                *(uint2*)&Bl[er * 64 + SW8(er, slot) + half] = lw;
            }
        }
        __syncthreads();
        // ---- MFMA: 3 products per fragment pair
#pragma unroll
        for (int ks = 0; ks < 2; ks++) {
            short8 afh[2], afl[2], bfh[2], bfl[2];
#pragma unroll
            for (int i = 0; i < 2; i++) {
                int row = wm + i * 16 + m16;
                afh[i] = *(const short8*)&Ah[row * 64 + SW8(row, 4 * ks + g)];
                afl[i] = *(const short8*)&Al[row * 64 + SW8(row, 4 * ks + g)];
            }
#pragma unroll
            for (int j = 0; j < 2; j++) {
                int row = wn + j * 16 + m16;
                bfh[j] = *(const short8*)&Bh[row * 64 + SW8(row, 4 * ks + g)];
                bfl[j] = *(const short8*)&Bl[row * 64 + SW8(row, 4 * ks + g)];
            }
#pragma unroll
            for (int i = 0; i < 2; i++)
#pragma unroll
                for (int j = 0; j < 2; j++) {
                    acc[i][j] = __builtin_amdgcn_mfma_f32_16x16x32_bf16(
                        afh[i], bfh[j], acc[i][j], 0, 0, 0);
                    acc[i][j] = __builtin_amdgcn_mfma_f32_16x16x32_bf16(
                        afh[i], bfl[j], acc[i][j], 0, 0, 0);
                    acc[i][j] = __builtin_amdgcn_mfma_f32_16x16x32_bf16(
                        afl[i], bfh[j], acc[i][j], 0, 0, 0);
                }
        }
    }

    bool hasScale = (scale != 0.f);
#pragma unroll
    for (int i = 0; i < 2; i++)
#pragma unroll
        for (int j = 0; j < 2; j++) {
            int row = mt * 64 + wm + i * 16 + g * 4;
            int col = nt * 64 + wn + j * 16 + m16;
#pragma unroll
            for (int r = 0; r < 4; r++) {
                size_t off = (size_t)(row + r) * DDIM + col;
                float v = sgn * acc[i][j][r];
                if (hasScale) v += scale * A[off];
                if (Add) v += Add[off];
                Dst[off] = v;
            }
        }
}

// copy one 64x64 tile of a 256x256 matrix
__device__ __forceinline__ void copy64(const float* __restrict__ src,
                                       float* __restrict__ dst,
                                       int mt, int nt) {
    int t = threadIdx.x;
    int r = mt * 64 + (t >> 2);
    int c0 = nt * 64 + (t & 3) * 16;
    const float* s = src + (size_t)r * DDIM + c0;
    float* d = dst + (size_t)r * DDIM + c0;
#pragma unroll
    for (int j = 0; j < 4; j++)
        *(float4*)(d + j * 4) = *(const float4*)(s + j * 4);
}

// ---------------------------------------------------------------------------
// Merged fused sums GEMM (both Skk and Svk in one launch, 1024 blocks):
//   which=0: Out=Skk, A=keys;  chunk-start windows also emit P = a*I - Skk
//   which=1: Out=Q (Svk), A=values
//   Out[n][m][e] = sum_{r} Asrc[l(r)][m] * (gamma[l(r)] * keys[l(r)][e])
// A-side + gammas register-prefetched across the batch-chunk loop (T14).
// ---------------------------------------------------------------------------
__global__ __launch_bounds__(256, 2) void sums_fused(
    const float* __restrict__ keys,
    const float* __restrict__ values,
    const float* __restrict__ gammas,
    float* __restrict__ Skk,
    float* __restrict__ Q,
    float* __restrict__ Pinit,
    const float* __restrict__ alpha_raw) {
    int which = blockIdx.x >> 9;
    int idx = blockIdx.x & 511;
    int nq = idx & 1;
    int mq = (idx >> 1) & 1;
    int n = idx >> 2;

    const float* Asrc = which ? values : keys;
    float* Out = which ? Q : Skk;

    __shared__ __align__(16) ushortT Asm[128 * 64];
    __shared__ __align__(16) ushortT Bsm[128 * 64];

    int t = threadIdx.x;
    int lane = t & 63, wv = t >> 6;
    int wm = (wv & 1) * 64, wn = (wv >> 1) * 64;
    int m16 = lane & 15, g = lane >> 4;

    int d0 = (t >> 3) * 4;
    int rqb = t & 7;

    floatx4 acc[4][4];
#pragma unroll
    for (int i = 0; i < 4; i++)
#pragma unroll
        for (int j = 0; j < 4; j++) acc[i][j] = (floatx4)0.f;

    floatx4 pa[2][4], pgv[2];
    {
        size_t lbase = (size_t)n * WWIN;
#pragma unroll
        for (int p = 0; p < 2; p++) {
            int r0 = (rqb + 8 * p) * 4;
            const float* Ar = Asrc + (lbase + r0) * DDIM + mq * 128 + d0;
            pa[p][0] = *(const floatx4*)Ar;
            pa[p][1] = *(const floatx4*)(Ar + DDIM);
            pa[p][2] = *(const floatx4*)(Ar + 2 * DDIM);
            pa[p][3] = *(const floatx4*)(Ar + 3 * DDIM);
            pgv[p] = *(const floatx4*)(gammas + lbase + r0);
        }
    }

    for (int c = 0; c < 8; c++) {
        size_t lbase = (size_t)c * LDIM + n * WWIN;
        __syncthreads();
#pragma unroll
        for (int p = 0; p < 2; p++) {
            int rq = rqb + 8 * p;
            int r0 = rq * 4;
            const float* Br = keys + (lbase + r0) * DDIM + nq * 128 + d0;
            floatx4 b0 = *(const floatx4*)Br;
            floatx4 b1 = *(const floatx4*)(Br + DDIM);
            floatx4 b2 = *(const floatx4*)(Br + 2 * DDIM);
            floatx4 b3 = *(const floatx4*)(Br + 3 * DDIM);
            floatx4 gv = pgv[p];
            b0 *= gv[0]; b1 *= gv[1]; b2 *= gv[2]; b3 *= gv[3];
            int slot = rq >> 1;
            int half = (rq & 1) * 4;
#pragma unroll
            for (int j = 0; j < 4; j++) {
                int dr = d0 + j;
                uint2 wa, wb;
                wa.x = (uintT)f2b(pa[p][0][j]) | ((uintT)f2b(pa[p][1][j]) << 16);
                wa.y = (uintT)f2b(pa[p][2][j]) | ((uintT)f2b(pa[p][3][j]) << 16);
                wb.x = (uintT)f2b(b0[j]) | ((uintT)f2b(b1[j]) << 16);
                wb.y = (uintT)f2b(b2[j]) | ((uintT)f2b(b3[j]) << 16);
                *(uint2*)&Asm[dr * 64 + SW8(dr, slot) + half] = wa;
                *(uint2*)&Bsm[dr * 64 + SW8(dr, slot) + half] = wb;
            }
        }
        if (c < 7) {
            size_t lb2 = lbase + LDIM;
#pragma unroll
            for (int p = 0; p < 2; p++) {
                int r0 = (rqb + 8 * p) * 4;
                const float* Ar = Asrc + (lb2 + r0) * DDIM + mq * 128 + d0;
                pa[p][0] = *(const floatx4*)Ar;
                pa[p][1] = *(const floatx4*)(Ar + DDIM);
                pa[p][2] = *(const floatx4*)(Ar + 2 * DDIM);
                pa[p][3] = *(const floatx4*)(Ar + 3 * DDIM);
                pgv[p] = *(const floatx4*)(gammas + lb2 + r0);
            }
        }
        __syncthreads();
#pragma unroll
        for (int ks = 0; ks < 2; ks++) {
            short8 af[4], bq[4];
#pragma unroll
            for (int i = 0; i < 4; i++) {
                int row = wm + i * 16 + m16;
                af[i] = *(const short8*)&Asm[row * 64 + SW8(row, 4 * ks + g)];
            }
#pragma unroll
            for (int j = 0; j < 4; j++) {
                int row = wn + j * 16 + m16;
                bq[j] = *(const short8*)&Bsm[row * 64 + SW8(row, 4 * ks + g)];
            }
#pragma unroll
            for (int i = 0; i < 4; i++)
#pragma unroll
                for (int j = 0; j < 4; j++)
                    acc[i][j] = __builtin_amdgcn_mfma_f32_16x16x32_bf16(
                        af[i], bq[j], acc[i][j], 0, 0, 0);
        }
    }

    float* Ob = Out + (size_t)n * MAT;
    bool doP = (which == 0) && ((n & (CHUNK - 1)) == 0);
    float aSig = doP ? dev_sigmoid(alpha_raw[0]) : 0.f;
#pragma unroll
    for (int i = 0; i < 4; i++)
#pragma unroll
        for (int j = 0; j < 4; j++)
#pragma unroll
            for (int r = 0; r < 4; r++) {
                int row = mq * 128 + wm + i * 16 + g * 4 + r;
                int col = nq * 128 + wn + j * 16 + m16;
                float v = acc[i][j][r];
                Ob[(size_t)row * DDIM + col] = v;
                if (doP) {
                    float* Pb = Pinit + (size_t)n * MAT;
                    Pb[(size_t)row * DDIM + col] =
                        ((row == col) ? aSig : 0.f) - v;
                }
            }
}

// ---------------------------------------------------------------------------
// MFMA retrieval: out[l][o] = sum_d q[l][d] * M[n(l)][o][d]
// q tile register-prefetched across the d-chunk loop (T14); M inline.
// ---------------------------------------------------------------------------
__global__ __launch_bounds__(256, 2) void out_mfma(
    const float* __restrict__ q,
    const float* __restrict__ Ms,
    float* __restrict__ out) {
    int op = blockIdx.x & 1;
    int rp = (blockIdx.x >> 1) & 3;
    int n = blockIdx.x >> 3;

    __shared__ __align__(16) ushortT Qsm[128 * 64];
    __shared__ __align__(16) ushortT Msm[128 * 64];

    int t = threadIdx.x;
    int lane = t & 63, wv = t >> 6;
    int wm = (wv & 1) * 64, wn = (wv >> 1) * 64;
    int m16 = lane & 15, g = lane >> 4;
    int f4 = t & 15;

    const float* Mbase = Ms + (size_t)n * MAT + (size_t)(op * 128) * DDIM;

    floatx4 acc[4][4];
#pragma unroll
    for (int i = 0; i < 4; i++)
#pragma unroll
        for (int j = 0; j < 4; j++) acc[i][j] = (floatx4)0.f;

    floatx4 qv[8];
    {
#pragma unroll
        for (int p = 0; p < 8; p++) {
            int row = (t >> 4) + p * 16;
            int b = rp * 2 + (row >> 6);
            int l = b * LDIM + n * WWIN + (row & 63);
            qv[p] = *(const floatx4*)&q[(size_t)l * DDIM + f4 * 4];
        }
    }

    for (int c = 0; c < 4; c++) {
        int d0 = c * 64;
        __syncthreads();
#pragma unroll
        for (int p = 0; p < 8; p++) {
            int row = (t >> 4) + p * 16;
            uint2 o2;
            o2.x = (uintT)f2b(qv[p][0]) | ((uintT)f2b(qv[p][1]) << 16);
            o2.y = (uintT)f2b(qv[p][2]) | ((uintT)f2b(qv[p][3]) << 16);
            *(uint2*)&Qsm[row * 64 + SW8(row, f4 >> 1) + (f4 & 1) * 4] = o2;
        }
#pragma unroll
        for (int p = 0; p < 4; p++) {
            int o = (t >> 3) + p * 32;
            int dg = t & 7;
            const floatx4* src =
                (const floatx4*)&Mbase[(size_t)o * DDIM + d0 + dg * 8];
            floatx4 m0 = src[0];
            floatx4 m1 = src[1];
            uint4 w;
            w.x = (uintT)f2b(m0[0]) | ((uintT)f2b(m0[1]) << 16);
            w.y = (uintT)f2b(m0[2]) | ((uintT)f2b(m0[3]) << 16);
            w.z = (uintT)f2b(m1[0]) | ((uintT)f2b(m1[1]) << 16);
            w.w = (uintT)f2b(m1[2]) | ((uintT)f2b(m1[3]) << 16);
            *(uint4*)&Msm[o * 64 + SW8(o, dg)] = w;
        }
        if (c < 3) {
            int d1 = d0 + 64;
#pragma unroll
            for (int p = 0; p < 8; p++) {
                int row = (t >> 4) + p * 16;
                int b = rp * 2 + (row >> 6);
                int l = b * LDIM + n * WWIN + (row & 63);
                qv[p] = *(const floatx4*)&q[(size_t)l * DDIM + d1 + f4 * 4];
            }
        }
        __syncthreads();
#pragma unroll
        for (int ks = 0; ks < 2; ks++) {
            short8 af[4], bq[4];
#pragma unroll
            for (int i = 0; i < 4; i++) {
                int row = wm + i * 16 + m16;
                af[i] = *(const short8*)&Qsm[row * 64 + SW8(row, 4 * ks + g)];
            }
#pragma unroll
            for (int j = 0; j < 4; j++) {
                int row = wn + j * 16 + m16;
                bq[j] = *(const short8*)&Msm[row * 64 + SW8(row, 4 * ks + g)];
            }
#pragma unroll
            for (int i = 0; i < 4; i++)
#pragma unroll
                for (int j = 0; j < 4; j++)
                    acc[i][j] = __builtin_amdgcn_mfma_f32_16x16x32_bf16(
                        af[i], bq[j], acc[i][j], 0, 0, 0);
        }
    }

#pragma unroll
    for (int i = 0; i < 4; i++)
#pragma unroll
        for (int r = 0; r < 4; r++) {
            int row = wm + i * 16 + g * 4 + r;
            int b = rp * 2 + (row >> 6);
            size_t l = (size_t)b * LDIM + n * WWIN + (row & 63);
#pragma unroll
            for (int j = 0; j < 4; j++) {
                int col = op * 128 + wn + j * 16 + m16;
                out[l * DDIM + col] = acc[i][j][r];
            }
        }
}

// ---------------------------------------------------------------------------
// Scan kernels: split-bf16 MFMA, 64x64 tiles, 16 tile-blocks per matmul.
// ---------------------------------------------------------------------------
__global__ __launch_bounds__(256, 2) void phase1_kernel(
    const float* __restrict__ Skk,
    float* __restrict__ Q,
    float* __restrict__ P,
    const float* __restrict__ alpha_raw,
    int j) {
    __shared__ __align__(16) ushortT sm[4 * 64 * 64];
    float a = dev_sigmoid(alpha_raw[0]);
    int tile = blockIdx.x & 15, mt = tile >> 2, nt = tile & 3;
    int idx = blockIdx.x >> 4;
    int chunk = idx >> 1, target = idx & 1;
    int n = chunk * CHUNK + j;
    float* base = target ? Q : P;
    float* dst = base + (size_t)n * MAT;
    const float* Ab = base + (size_t)(n - 1) * MAT;
    const float* Addp = target ? dst : nullptr;
    scan64(sm, Ab, Skk + (size_t)n * MAT, Addp, dst, mt, nt, a, -1.f);
}

// Kogge-Stone step over the NCHUNK chunk-tail carries:
//   Q'_c = Q_{c-s} @ P_c + Q_c ; P'_c = P_{c-s} @ P_c  (c>=s; copy else)
__global__ __launch_bounds__(256, 2) void ks_kernel(
    const float* __restrict__ srcQ,
    const float* __restrict__ srcP,
    float* __restrict__ dstQ,
    float* __restrict__ dstP,
    size_t sQs, size_t sPs, size_t dQs, size_t dPs,
    int s, int qonly) {
    __shared__ __align__(16) ushortT sm[4 * 64 * 64];
    int tile = blockIdx.x & 15, mt = tile >> 2, nt = tile & 3;
    int idx = blockIdx.x >> 4;
    int kind = qonly ? 0 : (idx & 1);
    int c = qonly ? idx : (idx >> 1);
    if (kind == 0) {
        float* D = dstQ + (size_t)c * dQs;
        if (c < s) {
            copy64(srcQ + (size_t)c * sQs, D, mt, nt);
        } else {
            scan64(sm, srcQ + (size_t)(c - s) * sQs, srcP + (size_t)c * sPs,
                   srcQ + (size_t)c * sQs, D, mt, nt, 0.f, 1.f);
        }
    } else {
        float* D = dstP + (size_t)c * dPs;
        if (c < s) {
            copy64(srcP + (size_t)c * sPs, D, mt, nt);
        } else {
            scan64(sm, srcP + (size_t)(c - s) * sPs, srcP + (size_t)c * sPs,
                   nullptr, D, mt, nt, 0.f, 1.f);
        }
    }
}

__global__ __launch_bounds__(256, 2) void phase3_kernel(
    float* __restrict__ Q,
    const float* __restrict__ P) {
    __shared__ __align__(16) ushortT sm[4 * 64 * 64];
    int tile = blockIdx.x & 15, mt = tile >> 2, nt = tile & 3;
    int w = blockIdx.x >> 4;
    int c = 1 + w / (CHUNK - 1);
    int j = w - (c - 1) * (CHUNK - 1);
    int n = c * CHUNK + j;
    int s = c * CHUNK - 1;
    float* d = Q + (size_t)n * MAT;
    scan64(sm, Q + (size_t)s * MAT, P + (size_t)n * MAT, d, d,
           mt, nt, 0.f, 1.f);
}

// ---------------------------------------------------------------------------
extern "C" void kernel_launch(void* const* d_in, const int* in_sizes, int n_in,
                              void* d_out, int out_size, void* d_ws, size_t ws_size,
                              hipStream_t stream) {
    const float* keys    = (const float*)d_in[0];
    const float* values  = (const float*)d_in[1];
    const float* queries = (const float*)d_in[2];
    const float* gammas  = (const float*)d_in[3];
    const float* alpha   = (const float*)d_in[4];
    float* outp = (float*)d_out;

    // Workspace layout (128 MB peak):
    //  A [0,32M):    Skk f32
    //  B [32,64M):   Q f32 (Svk -> prefix -> final Ms)
    //  C [64,96M):   P f32
    //  D [96,128M):  KS ping-pong tail buffers (T1Q,T1P,T2Q,T2P, 8MB each)
    char* ws = (char*)d_ws;
    float* Skk = (float*)ws;
    float* Q   = (float*)(ws + (size_t)32 * 1024 * 1024);
    float* P   = (float*)(ws + (size_t)64 * 1024 * 1024);
    char*  rD  = ws + (size_t)96 * 1024 * 1024;
    float* T1Q = (float*)rD;
    float* T1P = (float*)(rD + (size_t)8 * 1024 * 1024);
    float* T2Q = (float*)(rD + (size_t)16 * 1024 * 1024);
    float* T2P = (float*)(rD + (size_t)24 * 1024 * 1024);

    // 1) Skk (+ chunk-start P = aI - Skk) and Svk in ONE merged launch
    sums_fused<<<2 * NWIN * 4, 256, 0, stream>>>(keys, values, gammas,
                                                 Skk, Q, P, alpha);

    // 2) scan: chunk-local pass (CHUNK=4 -> 3 stages, 1024 blocks each)
    for (int j = 1; j < CHUNK; j++)
        phase1_kernel<<<NCHUNK * 2 * 16, 256, 0, stream>>>(Skk, Q, P, alpha, j);

    // 3) cross-chunk Kogge-Stone on the 32 tails (e_c = 4c+3), 5 steps
    ks_kernel<<<NCHUNK * 2 * 16, 256, 0, stream>>>(
        Q + 3 * MAT, P + 3 * MAT, T1Q, T1P,
        4 * MAT, 4 * MAT, MAT, MAT, 1, 0);
    ks_kernel<<<NCHUNK * 2 * 16, 256, 0, stream>>>(
        T1Q, T1P, T2Q, T2P, MAT, MAT, MAT, MAT, 2, 0);
    ks_kernel<<<NCHUNK * 2 * 16, 256, 0, stream>>>(
        T2Q, T2P, T1Q, T1P, MAT, MAT, MAT, MAT, 4, 0);
    ks_kernel<<<NCHUNK * 2 * 16, 256, 0, stream>>>(
        T1Q, T1P, T2Q, T2P, MAT, MAT, MAT, MAT, 8, 0);
    ks_kernel<<<NCHUNK * 16, 256, 0, stream>>>(
        T2Q, T2P, Q + 3 * MAT, nullptr, MAT, MAT, 4 * MAT, 0, 16, 1);

    // 4) broadcast tails into non-tail windows (31 chunks x 3 windows)
    phase3_kernel<<<(NCHUNK - 1) * (CHUNK - 1) * 16, 256, 0, stream>>>(Q, P);

    // 5) retrieval (M converted f32->bf16 in-flight)
    out_mfma<<<NWIN * 8, 256, 0, stream>>>(queries, Q, outp);
}